// Round 3
// baseline (2179.156 us; speedup 1.0000x reference)
//
#include <hip/hip_runtime.h>
#include <stdint.h>

// ---------------------------------------------------------------------------
// SphereViT forward on gfx950.  Inputs/outputs fp32 (flag-sniffed, R5-verified
// flag=1 world).  Residual fp32 in ws; GEMMs bf16 MFMA 16x16x32.
// R7 (2nd resubmit after broker timeouts): fused attention (QK^T + cross-head
// standardization + softmax + PV) in a single kernel per (b, 16-row tile)
// with dots held in 128KB LDS.  Removes the dots fp32 (67 MB/layer) and attn
// bf16 (34 MB/layer) HBM round-trips and 24 dispatches.  TBAA discipline:
// within any barrier-free span all LDS traffic is scalar float; f32x4
// fragment reads are barrier-separated from the float writes that produced
// them.
// ---------------------------------------------------------------------------

typedef __attribute__((ext_vector_type(8))) short short8;   // 8 x bf16
typedef __attribute__((ext_vector_type(4))) float f32x4;    // MFMA C/D frag

#define EPS 1e-5f

__device__ __forceinline__ float b2f(ushort u) {
    union { uint32_t i; float f; } c; c.i = ((uint32_t)u) << 16; return c.f;
}
__device__ __forceinline__ ushort f2b(float f) {
    union { float f; uint32_t i; } c; c.f = f;
    uint32_t u = c.i;
    uint32_t r = (u + 0x7fffu + ((u >> 16) & 1u)) >> 16;   // RNE
    return (ushort)r;
}
__device__ __forceinline__ float pack2(ushort lo, ushort hi) {
    union { uint32_t u; float f; } c;
    c.u = (uint32_t)lo | ((uint32_t)hi << 16);
    return c.f;
}
__device__ __forceinline__ short8 as_short8(f32x4 v) {
    union { f32x4 f; short8 s; } u; u.f = v; return u.s;
}
__device__ __forceinline__ void async16(const ushort* g, ushort* l) {
    __builtin_amdgcn_global_load_lds(
        (const __attribute__((address_space(1))) uint32_t*)g,
        (__attribute__((address_space(3))) uint32_t*)l, 16, 0, 0);
}

// block-wide sum of (s, ss) for 256-thread blocks (4 waves)
__device__ __forceinline__ float2 block_sum2(float s, float ss, int tid) {
    #pragma unroll
    for (int o = 32; o; o >>= 1) { s += __shfl_xor(s, o); ss += __shfl_xor(ss, o); }
    __shared__ float ps[4], pss[4];
    int w = tid >> 6;
    if ((tid & 63) == 0) { ps[w] = s; pss[w] = ss; }
    __syncthreads();
    return make_float2(ps[0] + ps[1] + ps[2] + ps[3],
                       pss[0] + pss[1] + pss[2] + pss[3]);
}

// ---------------------------------------------------------------------------
// Exact dtype sniffer on the all-ones nl_ln1_g tensor (R5: flag=1, fp32).
// ---------------------------------------------------------------------------
__global__ void sniff_dtype(const uint32_t* __restrict__ ones, int* __restrict__ flag) {
    if (threadIdx.x == 0 && blockIdx.x == 0) {
        int c32 = 0, c16 = 0;
        for (int i = 0; i < 256; i++) {
            uint32_t w = ones[i];
            c32 += (w == 0x3F800000u);
            c16 += (w == 0x3F803F80u);
        }
        *flag = (c32 >= c16) ? 1 : 0;
    }
}

// ---------------------------------------------------------------------------
// NT GEMM: C[M,N] = A[M,K]*Bt[N,K]^T (+bias).  A,Bt bf16 K-contiguous.
// 128x128 tile, BK=32, 4 waves (2x2 of 64x64).  global_load_lds staging.
// XCD swizzle: lid%8 -> xcd; each XCD owns an RM x RN tile region so its
// co-resident blocks share A/B panels in the 4 MiB per-XCD L2.
// MODE 0: store fp32 | 1: store bf16 | 2: fp32 +=
// ---------------------------------------------------------------------------
template <int MODE>
__global__ __launch_bounds__(256) void gemm_nt(
    const ushort* __restrict__ A, const ushort* __restrict__ Bt,
    const void* __restrict__ bias, int bias_off, const int* __restrict__ flagp,
    float* __restrict__ Cf, ushort* __restrict__ Cb,
    int M, int N, int K, int ldA, int ldB, int ldC, int RM, int RN)
{
    __shared__ ushort As[128 * 32];
    __shared__ ushort Bs[128 * 32];
    const int tid = threadIdx.x, lane = tid & 63, w = tid >> 6;

    // --- XCD-aware swizzle (bijective for any grid divisible into regions) ---
    int lid = blockIdx.y * gridDim.x + blockIdx.x;
    int xcd = lid & 7, slot = lid >> 3;
    int regions_n = gridDim.x / RN;           // regions along N
    int r_m = xcd / regions_n, r_n = xcd % regions_n;
    int tm = r_m * RM + slot / RN;
    int tn = r_n * RN + slot % RN;
    const int m0 = tm * 128, n0 = tn * 128;

    const int wr = (w >> 1) * 64, wc = (w & 1) * 64;
    const int m16 = lane & 15, quad = lane >> 4;

    f32x4 acc[4][4];
    #pragma unroll
    for (int i = 0; i < 4; i++)
        #pragma unroll
        for (int j = 0; j < 4; j++) acc[i][j] = (f32x4){0.f, 0.f, 0.f, 0.f};

    const int idx0 = (w * 2) * 64 + lane, idx1 = (w * 2 + 1) * 64 + lane;
    const int row0 = idx0 >> 2, ks0 = (idx0 & 3) * 8;
    const int row1 = idx1 >> 2, ks1 = (idx1 & 3) * 8;
    const ushort* a0 = A  + (size_t)(m0 + row0) * ldA + ks0;
    const ushort* a1 = A  + (size_t)(m0 + row1) * ldA + ks1;
    const ushort* b0 = Bt + (size_t)(n0 + row0) * ldB + ks0;
    const ushort* b1 = Bt + (size_t)(n0 + row1) * ldB + ks1;

    for (int k0 = 0; k0 < K; k0 += 32) {
        __syncthreads();                    // prev iter's LDS readers done
        async16(a0 + k0, As + (w * 2 + 0) * 512);
        async16(a1 + k0, As + (w * 2 + 1) * 512);
        async16(b0 + k0, Bs + (w * 2 + 0) * 512);
        async16(b1 + k0, Bs + (w * 2 + 1) * 512);
        __syncthreads();                    // compiler drains vmcnt before barrier
        short8 a[4], b[4];
        #pragma unroll
        for (int t = 0; t < 4; t++)
            a[t] = *(const short8*)(As + (wr + t * 16 + m16) * 32 + quad * 8);
        #pragma unroll
        for (int t = 0; t < 4; t++)
            b[t] = *(const short8*)(Bs + (wc + t * 16 + m16) * 32 + quad * 8);
        #pragma unroll
        for (int i = 0; i < 4; i++)
            #pragma unroll
            for (int j = 0; j < 4; j++)
                acc[i][j] = __builtin_amdgcn_mfma_f32_16x16x32_bf16(a[i], b[j], acc[i][j], 0, 0, 0);
    }

    float bvals[4] = {0.f, 0.f, 0.f, 0.f};
    if (bias) {
        if (*flagp) {
            #pragma unroll
            for (int j = 0; j < 4; j++)
                bvals[j] = ((const float*)bias)[bias_off + n0 + wc + j * 16 + m16];
        } else {
            #pragma unroll
            for (int j = 0; j < 4; j++)
                bvals[j] = b2f(((const ushort*)bias)[bias_off + n0 + wc + j * 16 + m16]);
        }
    }
    #pragma unroll
    for (int i = 0; i < 4; i++)
        #pragma unroll
        for (int j = 0; j < 4; j++)
            #pragma unroll
            for (int r = 0; r < 4; r++) {
                int row = m0 + wr + i * 16 + quad * 4 + r;
                int col = n0 + wc + j * 16 + m16;
                float v = acc[i][j][r] + bvals[j];
                if (MODE == 0)      Cf[(size_t)row * ldC + col] = v;
                else if (MODE == 1) Cb[(size_t)row * ldC + col] = f2b(v);
                else                Cf[(size_t)row * ldC + col] += v;
            }
}

// ---------------------------------------------------------------------------
// Transpose W[K,N] -> Wt[N,K] bf16, reading fp32 or bf16 source.
// ---------------------------------------------------------------------------
__global__ __launch_bounds__(256) void transpose_k(
    const void* __restrict__ W, size_t eoff, ushort* __restrict__ Wt,
    int K, int N, const int* __restrict__ flagp)
{
    __shared__ ushort t[32][33];
    int f32 = *flagp;
    int n0 = blockIdx.x * 32, k0 = blockIdx.y * 32;
    int tx = threadIdx.x & 31, ty = threadIdx.x >> 5;
    if (f32) {
        const float* Wf = (const float*)W + eoff;
        #pragma unroll
        for (int i = ty; i < 32; i += 8) t[i][tx] = f2b(Wf[(size_t)(k0 + i) * N + n0 + tx]);
    } else {
        const ushort* Wb = (const ushort*)W + eoff;
        #pragma unroll
        for (int i = ty; i < 32; i += 8) t[i][tx] = Wb[(size_t)(k0 + i) * N + n0 + tx];
    }
    __syncthreads();
    #pragma unroll
    for (int i = ty; i < 32; i += 8) Wt[(size_t)(n0 + i) * K + k0 + tx] = t[tx][i];
}

// Dtype-convert copy (8 elems/thread), for conv_w (already [N,K] layout).
__global__ __launch_bounds__(256) void convert_copy(
    const void* __restrict__ src, ushort* __restrict__ dst,
    const int* __restrict__ flagp)
{
    size_t i = ((size_t)blockIdx.x * 256 + threadIdx.x) * 8;
    if (*flagp) {
        const float* s = (const float*)src + i;
        ushort t[8];
        #pragma unroll
        for (int x = 0; x < 8; x++) t[x] = f2b(s[x]);
        *(uint4*)(dst + i) = *(uint4*)t;
    } else {
        *(uint4*)(dst + i) = *(const uint4*)((const ushort*)src + i);
    }
}

// ---------------------------------------------------------------------------
// Patch gather: img[b,c,256,512] -> A[(b,h,w)][(c,p,q)] bf16 (4096x3072)
// ---------------------------------------------------------------------------
__global__ __launch_bounds__(256) void patch_gather(
    const void* __restrict__ img, ushort* __restrict__ Ap,
    const int* __restrict__ flagp)
{
    int t = blockIdx.x * 256 + threadIdx.x;
    int qc = t & 3;
    int p  = (t >> 2) & 31;
    int c  = (t >> 7) % 3;
    int rest = t / 384;
    int wg = rest & 15;
    int hg = (rest >> 4) & 7;
    int b  = rest >> 7;
    size_t si = ((size_t)((b * 3 + c) * 256 + hg * 32 + p)) * 512 + wg * 32 + qc * 8;
    size_t di = ((size_t)((b * 8 + hg) * 16 + wg)) * 3072 + c * 1024 + p * 32 + qc * 8;
    if (*flagp) {
        const float* s = (const float*)img + si;
        ushort tmp[8];
        #pragma unroll
        for (int x = 0; x < 8; x++) tmp[x] = f2b(s[x]);
        *(uint4*)(Ap + di) = *(uint4*)tmp;
    } else {
        *(uint4*)(Ap + di) = *(const uint4*)((const ushort*)img + si);
    }
}

// ---------------------------------------------------------------------------
// LayerNorm over 1024 (fp32 in) -> bf16 out.  g/b dual-dtype, +elem offset.
// ---------------------------------------------------------------------------
__global__ __launch_bounds__(256) void ln_f32_to_bf16(
    const float* __restrict__ X, const void* __restrict__ g,
    const void* __restrict__ b, int goff, const int* __restrict__ flagp,
    ushort* __restrict__ Y)
{
    int row = blockIdx.x, tid = threadIdx.x;
    float4 v = ((const float4*)(X + (size_t)row * 1024))[tid];
    float s = v.x + v.y + v.z + v.w;
    float ss = v.x * v.x + v.y * v.y + v.z * v.z + v.w * v.w;
    float2 r = block_sum2(s, ss, tid);
    float mu = r.x * (1.f / 1024.f);
    float var = fmaxf(r.y * (1.f / 1024.f) - mu * mu, 0.f);
    float rs = rsqrtf(var + EPS);
    int c0 = tid * 4;
    float gv[4], bv[4];
    if (*flagp) {
        #pragma unroll
        for (int x = 0; x < 4; x++) { gv[x] = ((const float*)g)[goff + c0 + x]; bv[x] = ((const float*)b)[goff + c0 + x]; }
    } else {
        #pragma unroll
        for (int x = 0; x < 4; x++) { gv[x] = b2f(((const ushort*)g)[goff + c0 + x]); bv[x] = b2f(((const ushort*)b)[goff + c0 + x]); }
    }
    ushort4 o4;
    o4.x = f2b((v.x - mu) * rs * gv[0] + bv[0]);
    o4.y = f2b((v.y - mu) * rs * gv[1] + bv[1]);
    o4.z = f2b((v.z - mu) * rs * gv[2] + bv[2]);
    o4.w = f2b((v.w - mu) * rs * gv[3] + bv[3]);
    *(ushort4*)(Y + (size_t)row * 1024 + c0) = o4;
}

// LN over 1024 in-place fp32, then add spherical positional embedding
__global__ __launch_bounds__(256) void ln2_pos(
    float* __restrict__ X, const void* __restrict__ g, const void* __restrict__ b,
    const void* __restrict__ sph_pos, const void* __restrict__ pos_w,
    const void* __restrict__ pos_b, const int* __restrict__ flagp)
{
    int f32 = *flagp;
    int row = blockIdx.x, tid = threadIdx.x;
    float4 v = ((const float4*)(X + (size_t)row * 1024))[tid];
    float s = v.x + v.y + v.z + v.w;
    float ss = v.x * v.x + v.y * v.y + v.z * v.z + v.w * v.w;
    float2 r = block_sum2(s, ss, tid);
    float mu = r.x * (1.f / 1024.f);
    float var = fmaxf(r.y * (1.f / 1024.f) - mu * mu, 0.f);
    float rs = rsqrtf(var + EPS);
    int n = row & 127;
    int c0 = tid * 4;
    float s0, s1, gv[4], bv[4], w0[4], w1[4], pb[4];
    if (f32) {
        s0 = ((const float*)sph_pos)[n * 2 + 0]; s1 = ((const float*)sph_pos)[n * 2 + 1];
        #pragma unroll
        for (int x = 0; x < 4; x++) {
            gv[x] = ((const float*)g)[c0 + x];  bv[x] = ((const float*)b)[c0 + x];
            w0[x] = ((const float*)pos_w)[c0 + x]; w1[x] = ((const float*)pos_w)[1024 + c0 + x];
            pb[x] = ((const float*)pos_b)[c0 + x];
        }
    } else {
        s0 = b2f(((const ushort*)sph_pos)[n * 2 + 0]); s1 = b2f(((const ushort*)sph_pos)[n * 2 + 1]);
        #pragma unroll
        for (int x = 0; x < 4; x++) {
            gv[x] = b2f(((const ushort*)g)[c0 + x]);  bv[x] = b2f(((const ushort*)b)[c0 + x]);
            w0[x] = b2f(((const ushort*)pos_w)[c0 + x]); w1[x] = b2f(((const ushort*)pos_w)[1024 + c0 + x]);
            pb[x] = b2f(((const ushort*)pos_b)[c0 + x]);
        }
    }
    float4 o;
    o.x = (v.x - mu) * rs * gv[0] + bv[0] + s0 * w0[0] + s1 * w1[0] + pb[0];
    o.y = (v.y - mu) * rs * gv[1] + bv[1] + s0 * w0[1] + s1 * w1[1] + pb[1];
    o.z = (v.z - mu) * rs * gv[2] + bv[2] + s0 * w0[2] + s1 * w1[2] + pb[2];
    o.w = (v.w - mu) * rs * gv[3] + bv[3] + s0 * w0[3] + s1 * w1[3] + pb[3];
    *(float4*)(X + (size_t)row * 1024 + c0) = o;
}

// ---------------------------------------------------------------------------
// Fused attention per (b, 16-row i-tile).  Grid 256 = 32 b x 8 itiles; one
// block per CU.  b = blockIdx&31 -> all 8 blocks of a b land on one XCD so
// K/V (512KB/b) stay in that XCD's L2.
//
// Phases (per block):
//   A: QK^T for all 16 heads (Q/K fragments read straight from global),
//      dots[h][i][j] = qk*0.125*(1+sph) -> LDS fp32 (128 KB).      [barrier]
//   B: per (i,j): mu & 1/sd over 16 heads (ddof=1) -> musd LDS.    [barrier]
//   C: per (h,i) row: standardize, softmax over j (64-lane shfl
//      reduce, 2 j per lane), write P bf16 packed 2-per-word into
//      the LOW half of head h's dots storage.  Safe in-place: row
//      i's 64-word P slot [i*64, i*64+64) only clobbers dots words
//      of rows <= i/2 (already consumed; i ascending), and all
//      accesses in this span are scalar float (no TBAA reorder).   [barrier]
//   E (x4): stage V^T (packed pairs) into the freed HIGH halves of
//      this wave's 4 head regions, [barrier], PV MFMA from f32x4
//      reads of P and V^T, store o bf16, [barrier].
// ---------------------------------------------------------------------------
__global__ __launch_bounds__(256) void attn_fused(
    const ushort* __restrict__ qkv, const void* __restrict__ sph_dist,
    const int* __restrict__ flagp, ushort* __restrict__ o)
{
    __shared__ float dotsf[16 * 16 * 128];   // 128 KB: dots, then P/Vt overlay
    __shared__ float musd[16 * 128 * 2];     // 16 KB: (mu, rsd) per (i,j)
    const int tid = threadIdx.x, lane = tid & 63, w = tid >> 6;
    const int m16 = lane & 15, quad = lane >> 4;
    const int b = blockIdx.x & 31, i0 = (blockIdx.x >> 5) * 16;
    const int f32 = *flagp;

    // sph multipliers for this lane's output fragment (shared by 4 heads)
    float sphm[8][4];
    #pragma unroll
    for (int ct = 0; ct < 8; ct++)
        #pragma unroll
        for (int r = 0; r < 4; r++) {
            int i = i0 + quad * 4 + r, j = ct * 16 + m16;
            float sd = f32 ? ((const float*)sph_dist)[i * 128 + j]
                           : b2f(((const ushort*)sph_dist)[i * 128 + j]);
            sphm[ct][r] = 0.125f * (1.f + sd);
        }

    // ---- Phase A: QK^T (wave w owns heads 4w..4w+3) ----
    const ushort* qrow = qkv + (size_t)(b * 128 + i0 + m16) * 3072 + quad * 8;
    const ushort* krow = qkv + (size_t)(b * 128 + m16) * 3072 + 1024 + quad * 8;
    #pragma unroll
    for (int hh = 0; hh < 4; hh++) {
        const int h = w * 4 + hh;
        short8 qa0 = *(const short8*)(qrow + h * 64);
        short8 qa1 = *(const short8*)(qrow + h * 64 + 32);
        f32x4 acc[8];
        #pragma unroll
        for (int ct = 0; ct < 8; ct++) acc[ct] = (f32x4){0.f, 0.f, 0.f, 0.f};
        #pragma unroll
        for (int ct = 0; ct < 8; ct++) {
            const ushort* kp = krow + (size_t)ct * 16 * 3072 + h * 64;
            short8 k0 = *(const short8*)(kp);
            short8 k1 = *(const short8*)(kp + 32);
            acc[ct] = __builtin_amdgcn_mfma_f32_16x16x32_bf16(qa0, k0, acc[ct], 0, 0, 0);
            acc[ct] = __builtin_amdgcn_mfma_f32_16x16x32_bf16(qa1, k1, acc[ct], 0, 0, 0);
        }
        #pragma unroll
        for (int ct = 0; ct < 8; ct++)
            #pragma unroll
            for (int r = 0; r < 4; r++)
                dotsf[h * 2048 + (quad * 4 + r) * 128 + ct * 16 + m16] =
                    acc[ct][r] * sphm[ct][r];
    }
    __syncthreads();

    // ---- Phase B: cross-head mean / 1/std per (i,j) ----
    #pragma unroll
    for (int p = 0; p < 8; p++) {
        int idx = p * 256 + tid, i = idx >> 7, j = idx & 127;
        float v[16], s = 0.f;
        #pragma unroll
        for (int h = 0; h < 16; h++) { v[h] = dotsf[h * 2048 + i * 128 + j]; s += v[h]; }
        float mu = s * (1.f / 16.f), q = 0.f;
        #pragma unroll
        for (int h = 0; h < 16; h++) { float d = v[h] - mu; q += d * d; }
        float rsd = rsqrtf(fmaxf(q * (1.f / 15.f), 1e-20f));
        musd[(i * 128 + j) * 2]     = mu;
        musd[(i * 128 + j) * 2 + 1] = rsd;
    }
    __syncthreads();

    // ---- Phase C: row softmax, P packed in-place (lane owns j=2l,2l+1) ----
    #pragma unroll
    for (int hh = 0; hh < 4; hh++) {
        const int h = w * 4 + hh;
        #pragma unroll
        for (int i = 0; i < 16; i++) {
            float x0 = dotsf[h * 2048 + i * 128 + 2 * lane];
            float x1 = dotsf[h * 2048 + i * 128 + 2 * lane + 1];
            float4 ms = *(const float4*)&musd[i * 256 + 4 * lane];
            x0 = (x0 - ms.x) * ms.y;
            x1 = (x1 - ms.z) * ms.w;
            float m = fmaxf(x0, x1);
            #pragma unroll
            for (int o2 = 32; o2; o2 >>= 1) m = fmaxf(m, __shfl_xor(m, o2));
            float e0 = __expf(x0 - m), e1 = __expf(x1 - m);
            float s = e0 + e1;
            #pragma unroll
            for (int o2 = 32; o2; o2 >>= 1) s += __shfl_xor(s, o2);
            float inv = 1.f / s;
            dotsf[h * 2048 + i * 64 + (lane ^ ((i & 7) << 2))] =
                pack2(f2b(e0 * inv), f2b(e1 * inv));
        }
    }
    __syncthreads();

    // ---- Phase E: per head: stage V^T into freed halves, PV, store o ----
    #pragma unroll 1
    for (int g = 0; g < 4; g++) {
        const int h = w * 4 + g;
        {
            // lane stages V rows 2l, 2l+1; word (d, pair l) = (V[2l][d], V[2l+1][d])
            const ushort* vr0 = qkv + (size_t)(b * 128 + 2 * lane) * 3072 + 2048 + h * 64;
            const ushort* vr1 = vr0 + 3072;
            short8 r0[8], r1[8];
            #pragma unroll
            for (int x = 0; x < 8; x++) {
                r0[x] = *(const short8*)(vr0 + x * 8);
                r1[x] = *(const short8*)(vr1 + x * 8);
            }
            #pragma unroll
            for (int d = 0; d < 64; d++)
                dotsf[(w * 4 + (d >> 4)) * 2048 + 1024 + (d & 15) * 64 +
                      (lane ^ ((d & 7) << 2))] =
                    pack2((ushort)r0[d >> 3][d & 7], (ushort)r1[d >> 3][d & 7]);
        }
        __syncthreads();
        f32x4 pacc[4];
        #pragma unroll
        for (int ct = 0; ct < 4; ct++) pacc[ct] = (f32x4){0.f, 0.f, 0.f, 0.f};
        const int sw = (m16 & 7) << 2;
        #pragma unroll
        for (int kq = 0; kq < 4; kq++) {
            f32x4 paw = *(const f32x4*)&dotsf[h * 2048 + m16 * 64 +
                                              ((kq * 16 + quad * 4) ^ sw)];
            short8 pa = as_short8(paw);
            #pragma unroll
            for (int ct = 0; ct < 4; ct++) {
                f32x4 vbw = *(const f32x4*)&dotsf[(w * 4 + ct) * 2048 + 1024 + m16 * 64 +
                                                  ((kq * 16 + quad * 4) ^ sw)];
                pacc[ct] = __builtin_amdgcn_mfma_f32_16x16x32_bf16(pa, as_short8(vbw), pacc[ct], 0, 0, 0);
            }
        }
        #pragma unroll
        for (int ct = 0; ct < 4; ct++)
            #pragma unroll
            for (int r = 0; r < 4; r++)
                o[(size_t)(b * 128 + i0 + quad * 4 + r) * 1024 + h * 64 + ct * 16 + m16] =
                    f2b(pacc[ct][r]);
        __syncthreads();
    }
}

// ---------------------------------------------------------------------------
// Final LN over 3072 (bf16 in) + un-patchify; writes fp32 OR bf16 per flag.
// ---------------------------------------------------------------------------
__global__ __launch_bounds__(256) void out_ln_rearrange(
    const ushort* __restrict__ Y, const void* __restrict__ g,
    const void* __restrict__ bb, const int* __restrict__ flagp,
    void* __restrict__ out)
{
    __shared__ float rowbuf[3072];
    int f32 = *flagp;
    int r = blockIdx.x;
    int b = r >> 7, n = r & 127, hg = n >> 4, wg = n & 15;
    int tid = threadIdx.x;
    float s = 0.f, ss = 0.f;
    #pragma unroll
    for (int x = 0; x < 3; x++) {
        ushort4 u = *(const ushort4*)(Y + (size_t)r * 3072 + (size_t)(x * 256 + tid) * 4);
        float4 v = make_float4(b2f(u.x), b2f(u.y), b2f(u.z), b2f(u.w));
        *(float4*)(rowbuf + (x * 256 + tid) * 4) = v;
        s += v.x + v.y + v.z + v.w;
        ss += v.x * v.x + v.y * v.y + v.z * v.z + v.w * v.w;
    }
    float2 red = block_sum2(s, ss, tid);   // barrier makes rowbuf visible
    float mu = red.x * (1.f / 3072.f);
    float var = fmaxf(red.y * (1.f / 3072.f) - mu * mu, 0.f);
    float rs = rsqrtf(var + EPS);
    int p1 = tid >> 3, sj = tid & 7;
    #pragma unroll
    for (int c = 0; c < 3; c++) {
        float vals[4];
        #pragma unroll
        for (int x = 0; x < 4; x++) {
            int p2 = sj * 4 + x;
            int col = p1 * 96 + p2 * 3 + c;
            float gv, bv;
            if (f32) { gv = ((const float*)g)[col];  bv = ((const float*)bb)[col]; }
            else     { gv = b2f(((const ushort*)g)[col]); bv = b2f(((const ushort*)bb)[col]); }
            vals[x] = (rowbuf[col] - mu) * rs * gv + bv;
        }
        size_t di = (size_t)((b * 3 + c) * 256 + hg * 32 + p1) * 512 + wg * 32 + sj * 4;
        if (f32) {
            *(float4*)((float*)out + di) = make_float4(vals[0], vals[1], vals[2], vals[3]);
        } else {
            ushort4 o4;
            #pragma unroll
            for (int x = 0; x < 4; x++) ((ushort*)&o4)[x] = f2b(vals[x]);
            *(ushort4*)((ushort*)out + di) = o4;
        }
    }
}

// ---------------------------------------------------------------------------
// Host-side orchestration
// ---------------------------------------------------------------------------
extern "C" void kernel_launch(void* const* d_in, const int* in_sizes, int n_in,
                              void* d_out, int out_size, void* d_ws, size_t ws_size,
                              hipStream_t stream)
{
    const void* img      = d_in[0];
    const void* sph_pos  = d_in[1];
    const void* sph_dist = d_in[2];
    const void* conv_w   = d_in[3];
    const void* conv_b   = d_in[4];
    const void* nl1g     = d_in[5];
    const void* nl1b     = d_in[6];
    const void* nl_w     = d_in[7];
    const void* nl_b     = d_in[8];
    const void* nl2g     = d_in[9];
    const void* nl2b     = d_in[10];
    const void* pos_w    = d_in[11];
    const void* pos_b    = d_in[12];
    const void* ln_g     = d_in[13];
    const void* ln_b     = d_in[14];
    const void* wqkv     = d_in[15];
    const void* wo       = d_in[16];
    const void* wo_b     = d_in[17];
    const void* trg      = d_in[18];
    const void* trb      = d_in[19];
    const void* exp_w    = d_in[20];
    const void* exp_b    = d_in[21];
    const void* og       = d_in[22];
    const void* ob       = d_in[23];

    // --- workspace layout: 88 MiB + flag ---
    char* ws = (char*)d_ws;
    float*  xf    = (float*) (ws + 0);            // [0,16M)   fp32 residual [4096,1024]
    ushort* xb    = (ushort*)(ws + 16777216);     // [16,24M)  bf16 LN out [4096,1024]
    ushort* qkvb  = (ushort*)(ws + 25165824);     // [24,48M)  bf16 qkv / patch-mat / expand-out
    float*  y1    = (float*) (ws + 50331648);     // fp32 patch-embed out (pre-loop)
    ushort* o_bf  = (ushort*)(ws + 50331648);     // overlay: bf16 attn out (in loop)
    ushort* wTa   = (ushort*)(ws + 83886080);     // [80,86M)  weight^T [3072,1024]
    ushort* wTb   = (ushort*)(ws + 90177536);     // [86,88M)  weight^T [1024,1024]
    int*    flagp = (int*)   (ws + 92274688);     // dtype flag (1 = fp32 world)

    sniff_dtype<<<1, 64, 0, stream>>>((const uint32_t*)nl1g, flagp);

    // patch embedding (patch matrix staged in qkvb region)
    patch_gather<<<6144, 256, 0, stream>>>(img, qkvb, flagp);
    convert_copy<<<1536, 256, 0, stream>>>(conv_w, wTa, flagp);   // 1024x3072 -> bf16
    gemm_nt<0><<<dim3(8, 32), 256, 0, stream>>>(qkvb, wTa, conv_b, 0, flagp, y1, nullptr,
                                                4096, 1024, 3072, 3072, 3072, 1024, 4, 8);
    // norm_linear
    ln_f32_to_bf16<<<4096, 256, 0, stream>>>(y1, nl1g, nl1b, 0, flagp, xb);
    transpose_k<<<dim3(32, 32), 256, 0, stream>>>(nl_w, 0, wTb, 1024, 1024, flagp);
    gemm_nt<0><<<dim3(8, 32), 256, 0, stream>>>(xb, wTb, nl_b, 0, flagp, xf, nullptr,
                                                4096, 1024, 1024, 1024, 1024, 1024, 4, 8);
    ln2_pos<<<4096, 256, 0, stream>>>(xf, nl2g, nl2b, sph_pos, pos_w, pos_b, flagp);

    // transformer blocks
    for (int l = 0; l < 12; l++) {
        transpose_k<<<dim3(96, 32), 256, 0, stream>>>(wqkv, (size_t)l * 1024 * 3072, wTa, 1024, 3072, flagp);
        transpose_k<<<dim3(32, 32), 256, 0, stream>>>(wo, (size_t)l * 1024 * 1024, wTb, 1024, 1024, flagp);
        ln_f32_to_bf16<<<4096, 256, 0, stream>>>(xf, ln_g, ln_b, l * 1024, flagp, xb);
        gemm_nt<1><<<dim3(24, 32), 256, 0, stream>>>(xb, wTa, nullptr, 0, flagp, nullptr, qkvb,
                                                     4096, 3072, 1024, 1024, 1024, 3072, 8, 12);
        attn_fused<<<256, 256, 0, stream>>>(qkvb, sph_dist, flagp, o_bf);
        gemm_nt<2><<<dim3(8, 32), 256, 0, stream>>>(o_bf, wTb, wo_b, l * 1024, flagp, xf, nullptr,
                                                    4096, 1024, 1024, 1024, 1024, 1024, 4, 8);
    }

    // final LN + expand head (bf16 into qkvb) + un-patchify (dtype per flag)
    ln_f32_to_bf16<<<4096, 256, 0, stream>>>(xf, trg, trb, 0, flagp, xb);
    transpose_k<<<dim3(96, 32), 256, 0, stream>>>(exp_w, 0, wTa, 1024, 3072, flagp);
    gemm_nt<1><<<dim3(24, 32), 256, 0, stream>>>(xb, wTa, exp_b, 0, flagp, nullptr, qkvb,
                                                 4096, 3072, 1024, 1024, 1024, 3072, 8, 12);
    out_ln_rearrange<<<4096, 256, 0, stream>>>(qkvb, og, ob, flagp, d_out);
}

// Round 7
// 2112.553 us; speedup vs baseline: 1.0315x; 1.0315x over previous
//
#include <hip/hip_runtime.h>
#include <stdint.h>

// ---------------------------------------------------------------------------
// SphereViT forward on gfx950.  Inputs/outputs fp32 (flag-sniffed, R5-verified
// flag=1 world).  Residual fp32 in ws; GEMMs bf16 MFMA 16x16x32.
// R8 (4th submit; all failures were GPU-acquisition-level, pre-execution):
// gemm_nt K-loop rebuilt as a triple-buffered pipeline with counted vmcnt
// (T3/T4-lite).  R7 post-mortem: attention fusion was neutral ->
// intermediates were LLC-resident; the real cost is the GEMMs' exposed
// HBM latency (issue loads -> full vmcnt(0) drain -> compute, at 1-3
// blocks/CU).  Now: prologue stages K-tiles 0,1; each iter issues tile
// t+2 and waits vmcnt(8) (never 0 mid-loop) so ~2 iterations of HBM
// latency stay in flight behind the MFMA phase.  Raw s_barrier (no
// compiler vmcnt(0) drain) + sched_barrier(0) pins (rule #18).
// Race audit: tile t+2 overwrites the buffer last read at iter t-1,
// separated by t-1's end barrier; per-wave vmcnt counts its own 4
// loads/tile, barrier publishes cross-wave.
// ---------------------------------------------------------------------------

typedef __attribute__((ext_vector_type(8))) short short8;   // 8 x bf16
typedef __attribute__((ext_vector_type(4))) float f32x4;    // MFMA C/D frag

#define EPS 1e-5f

__device__ __forceinline__ float b2f(ushort u) {
    union { uint32_t i; float f; } c; c.i = ((uint32_t)u) << 16; return c.f;
}
__device__ __forceinline__ ushort f2b(float f) {
    union { float f; uint32_t i; } c; c.f = f;
    uint32_t u = c.i;
    uint32_t r = (u + 0x7fffu + ((u >> 16) & 1u)) >> 16;   // RNE
    return (ushort)r;
}
__device__ __forceinline__ float pack2(ushort lo, ushort hi) {
    union { uint32_t u; float f; } c;
    c.u = (uint32_t)lo | ((uint32_t)hi << 16);
    return c.f;
}
__device__ __forceinline__ short8 as_short8(f32x4 v) {
    union { f32x4 f; short8 s; } u; u.f = v; return u.s;
}
__device__ __forceinline__ void async16(const ushort* g, ushort* l) {
    __builtin_amdgcn_global_load_lds(
        (const __attribute__((address_space(1))) uint32_t*)g,
        (__attribute__((address_space(3))) uint32_t*)l, 16, 0, 0);
}

// block-wide sum of (s, ss) for 256-thread blocks (4 waves)
__device__ __forceinline__ float2 block_sum2(float s, float ss, int tid) {
    #pragma unroll
    for (int o = 32; o; o >>= 1) { s += __shfl_xor(s, o); ss += __shfl_xor(ss, o); }
    __shared__ float ps[4], pss[4];
    int w = tid >> 6;
    if ((tid & 63) == 0) { ps[w] = s; pss[w] = ss; }
    __syncthreads();
    return make_float2(ps[0] + ps[1] + ps[2] + ps[3],
                       pss[0] + pss[1] + pss[2] + pss[3]);
}

// ---------------------------------------------------------------------------
// Exact dtype sniffer on the all-ones nl_ln1_g tensor (R5: flag=1, fp32).
// ---------------------------------------------------------------------------
__global__ void sniff_dtype(const uint32_t* __restrict__ ones, int* __restrict__ flag) {
    if (threadIdx.x == 0 && blockIdx.x == 0) {
        int c32 = 0, c16 = 0;
        for (int i = 0; i < 256; i++) {
            uint32_t w = ones[i];
            c32 += (w == 0x3F800000u);
            c16 += (w == 0x3F803F80u);
        }
        *flag = (c32 >= c16) ? 1 : 0;
    }
}

// ---------------------------------------------------------------------------
// NT GEMM: C[M,N] = A[M,K]*Bt[N,K]^T (+bias).  A,Bt bf16 K-contiguous.
// 128x128 tile, BK=32, 4 waves (2x2 of 64x64).  Triple-buffered
// global_load_lds staging with counted vmcnt (see header).
// XCD swizzle: lid%8 -> xcd; each XCD owns an RM x RN tile region so its
// co-resident blocks share A/B panels in the 4 MiB per-XCD L2.
// MODE 0: store fp32 | 1: store bf16 | 2: fp32 +=
// ---------------------------------------------------------------------------
template <int MODE>
__global__ __launch_bounds__(256) void gemm_nt(
    const ushort* __restrict__ A, const ushort* __restrict__ Bt,
    const void* __restrict__ bias, int bias_off, const int* __restrict__ flagp,
    float* __restrict__ Cf, ushort* __restrict__ Cb,
    int M, int N, int K, int ldA, int ldB, int ldC, int RM, int RN)
{
    __shared__ ushort As[3 * 128 * 32];   // 3 K-tile buffers, 8 KB each
    __shared__ ushort Bs[3 * 128 * 32];
    const int tid = threadIdx.x, lane = tid & 63, w = tid >> 6;

    // --- XCD-aware swizzle (bijective for any grid divisible into regions) ---
    int lid = blockIdx.y * gridDim.x + blockIdx.x;
    int xcd = lid & 7, slot = lid >> 3;
    int regions_n = gridDim.x / RN;           // regions along N
    int r_m = xcd / regions_n, r_n = xcd % regions_n;
    int tm = r_m * RM + slot / RN;
    int tn = r_n * RN + slot % RN;
    const int m0 = tm * 128, n0 = tn * 128;

    const int wr = (w >> 1) * 64, wc = (w & 1) * 64;
    const int m16 = lane & 15, quad = lane >> 4;

    f32x4 acc[4][4];
    #pragma unroll
    for (int i = 0; i < 4; i++)
        #pragma unroll
        for (int j = 0; j < 4; j++) acc[i][j] = (f32x4){0.f, 0.f, 0.f, 0.f};

    const int idx0 = (w * 2) * 64 + lane, idx1 = (w * 2 + 1) * 64 + lane;
    const int row0 = idx0 >> 2, ks0 = (idx0 & 3) * 8;
    const int row1 = idx1 >> 2, ks1 = (idx1 & 3) * 8;
    const ushort* a0 = A  + (size_t)(m0 + row0) * ldA + ks0;
    const ushort* a1 = A  + (size_t)(m0 + row1) * ldA + ks1;
    const ushort* b0 = Bt + (size_t)(n0 + row0) * ldB + ks0;
    const ushort* b1 = Bt + (size_t)(n0 + row1) * ldB + ks1;

    const int nt = K >> 5;                  // K-tiles of 32
    const int c0 = (w * 2 + 0) * 512;       // this wave's LDS chunk offsets
    const int c1 = (w * 2 + 1) * 512;

    // prologue: stage tiles 0 and 1 into buffers 0 and 1 (8 loads in flight)
    async16(a0, As + c0);
    async16(a1, As + c1);
    async16(b0, Bs + c0);
    async16(b1, Bs + c1);
    if (nt > 1) {
        async16(a0 + 32, As + 4096 + c0);
        async16(a1 + 32, As + 4096 + c1);
        async16(b0 + 32, Bs + 4096 + c0);
        async16(b1 + 32, Bs + 4096 + c1);
    }

    int cur = 0;
    for (int t = 0; t < nt; ++t) {
        int b2 = cur + 2; if (b2 >= 3) b2 -= 3;
        if (t + 2 < nt) {
            const int ko = (t + 2) * 32;
            async16(a0 + ko, As + b2 * 4096 + c0);
            async16(a1 + ko, As + b2 * 4096 + c1);
            async16(b0 + ko, Bs + b2 * 4096 + c0);
            async16(b1 + ko, Bs + b2 * 4096 + c1);
            asm volatile("s_waitcnt vmcnt(8)" ::: "memory");   // tile t landed
        } else if (t + 1 < nt) {
            asm volatile("s_waitcnt vmcnt(4)" ::: "memory");   // tile t landed
        } else {
            asm volatile("s_waitcnt vmcnt(0)" ::: "memory");   // last tile
        }
        __builtin_amdgcn_s_barrier();            // all waves' tile-t data in LDS
        __builtin_amdgcn_sched_barrier(0);       // no hoist above barrier

        const ushort* Ac = As + cur * 4096;
        const ushort* Bc = Bs + cur * 4096;
        short8 a[4], b[4];
        #pragma unroll
        for (int t4 = 0; t4 < 4; t4++)
            a[t4] = *(const short8*)(Ac + (wr + t4 * 16 + m16) * 32 + quad * 8);
        #pragma unroll
        for (int t4 = 0; t4 < 4; t4++)
            b[t4] = *(const short8*)(Bc + (wc + t4 * 16 + m16) * 32 + quad * 8);
        #pragma unroll
        for (int i = 0; i < 4; i++)
            #pragma unroll
            for (int j = 0; j < 4; j++)
                acc[i][j] = __builtin_amdgcn_mfma_f32_16x16x32_bf16(a[i], b[j], acc[i][j], 0, 0, 0);

        __builtin_amdgcn_sched_barrier(0);       // no sink below barrier
        __builtin_amdgcn_s_barrier();            // readers of buf[cur] done
        cur = (cur + 1 == 3) ? 0 : cur + 1;
    }

    float bvals[4] = {0.f, 0.f, 0.f, 0.f};
    if (bias) {
        if (*flagp) {
            #pragma unroll
            for (int j = 0; j < 4; j++)
                bvals[j] = ((const float*)bias)[bias_off + n0 + wc + j * 16 + m16];
        } else {
            #pragma unroll
            for (int j = 0; j < 4; j++)
                bvals[j] = b2f(((const ushort*)bias)[bias_off + n0 + wc + j * 16 + m16]);
        }
    }
    #pragma unroll
    for (int i = 0; i < 4; i++)
        #pragma unroll
        for (int j = 0; j < 4; j++)
            #pragma unroll
            for (int r = 0; r < 4; r++) {
                int row = m0 + wr + i * 16 + quad * 4 + r;
                int col = n0 + wc + j * 16 + m16;
                float v = acc[i][j][r] + bvals[j];
                if (MODE == 0)      Cf[(size_t)row * ldC + col] = v;
                else if (MODE == 1) Cb[(size_t)row * ldC + col] = f2b(v);
                else                Cf[(size_t)row * ldC + col] += v;
            }
}

// ---------------------------------------------------------------------------
// Transpose W[K,N] -> Wt[N,K] bf16, reading fp32 or bf16 source.
// ---------------------------------------------------------------------------
__global__ __launch_bounds__(256) void transpose_k(
    const void* __restrict__ W, size_t eoff, ushort* __restrict__ Wt,
    int K, int N, const int* __restrict__ flagp)
{
    __shared__ ushort t[32][33];
    int f32 = *flagp;
    int n0 = blockIdx.x * 32, k0 = blockIdx.y * 32;
    int tx = threadIdx.x & 31, ty = threadIdx.x >> 5;
    if (f32) {
        const float* Wf = (const float*)W + eoff;
        #pragma unroll
        for (int i = ty; i < 32; i += 8) t[i][tx] = f2b(Wf[(size_t)(k0 + i) * N + n0 + tx]);
    } else {
        const ushort* Wb = (const ushort*)W + eoff;
        #pragma unroll
        for (int i = ty; i < 32; i += 8) t[i][tx] = Wb[(size_t)(k0 + i) * N + n0 + tx];
    }
    __syncthreads();
    #pragma unroll
    for (int i = ty; i < 32; i += 8) Wt[(size_t)(n0 + i) * K + k0 + tx] = t[tx][i];
}

// Dtype-convert copy (8 elems/thread), for conv_w (already [N,K] layout).
__global__ __launch_bounds__(256) void convert_copy(
    const void* __restrict__ src, ushort* __restrict__ dst,
    const int* __restrict__ flagp)
{
    size_t i = ((size_t)blockIdx.x * 256 + threadIdx.x) * 8;
    if (*flagp) {
        const float* s = (const float*)src + i;
        ushort t[8];
        #pragma unroll
        for (int x = 0; x < 8; x++) t[x] = f2b(s[x]);
        *(uint4*)(dst + i) = *(uint4*)t;
    } else {
        *(uint4*)(dst + i) = *(const uint4*)((const ushort*)src + i);
    }
}

// ---------------------------------------------------------------------------
// Patch gather: img[b,c,256,512] -> A[(b,h,w)][(c,p,q)] bf16 (4096x3072)
// ---------------------------------------------------------------------------
__global__ __launch_bounds__(256) void patch_gather(
    const void* __restrict__ img, ushort* __restrict__ Ap,
    const int* __restrict__ flagp)
{
    int t = blockIdx.x * 256 + threadIdx.x;
    int qc = t & 3;
    int p  = (t >> 2) & 31;
    int c  = (t >> 7) % 3;
    int rest = t / 384;
    int wg = rest & 15;
    int hg = (rest >> 4) & 7;
    int b  = rest >> 7;
    size_t si = ((size_t)((b * 3 + c) * 256 + hg * 32 + p)) * 512 + wg * 32 + qc * 8;
    size_t di = ((size_t)((b * 8 + hg) * 16 + wg)) * 3072 + c * 1024 + p * 32 + qc * 8;
    if (*flagp) {
        const float* s = (const float*)img + si;
        ushort tmp[8];
        #pragma unroll
        for (int x = 0; x < 8; x++) tmp[x] = f2b(s[x]);
        *(uint4*)(Ap + di) = *(uint4*)tmp;
    } else {
        *(uint4*)(Ap + di) = *(const uint4*)((const ushort*)img + si);
    }
}

// ---------------------------------------------------------------------------
// LayerNorm over 1024 (fp32 in) -> bf16 out.  g/b dual-dtype, +elem offset.
// ---------------------------------------------------------------------------
__global__ __launch_bounds__(256) void ln_f32_to_bf16(
    const float* __restrict__ X, const void* __restrict__ g,
    const void* __restrict__ b, int goff, const int* __restrict__ flagp,
    ushort* __restrict__ Y)
{
    int row = blockIdx.x, tid = threadIdx.x;
    float4 v = ((const float4*)(X + (size_t)row * 1024))[tid];
    float s = v.x + v.y + v.z + v.w;
    float ss = v.x * v.x + v.y * v.y + v.z * v.z + v.w * v.w;
    float2 r = block_sum2(s, ss, tid);
    float mu = r.x * (1.f / 1024.f);
    float var = fmaxf(r.y * (1.f / 1024.f) - mu * mu, 0.f);
    float rs = rsqrtf(var + EPS);
    int c0 = tid * 4;
    float gv[4], bv[4];
    if (*flagp) {
        #pragma unroll
        for (int x = 0; x < 4; x++) { gv[x] = ((const float*)g)[goff + c0 + x]; bv[x] = ((const float*)b)[goff + c0 + x]; }
    } else {
        #pragma unroll
        for (int x = 0; x < 4; x++) { gv[x] = b2f(((const ushort*)g)[goff + c0 + x]); bv[x] = b2f(((const ushort*)b)[goff + c0 + x]); }
    }
    ushort4 o4;
    o4.x = f2b((v.x - mu) * rs * gv[0] + bv[0]);
    o4.y = f2b((v.y - mu) * rs * gv[1] + bv[1]);
    o4.z = f2b((v.z - mu) * rs * gv[2] + bv[2]);
    o4.w = f2b((v.w - mu) * rs * gv[3] + bv[3]);
    *(ushort4*)(Y + (size_t)row * 1024 + c0) = o4;
}

// LN over 1024 in-place fp32, then add spherical positional embedding
__global__ __launch_bounds__(256) void ln2_pos(
    float* __restrict__ X, const void* __restrict__ g, const void* __restrict__ b,
    const void* __restrict__ sph_pos, const void* __restrict__ pos_w,
    const void* __restrict__ pos_b, const int* __restrict__ flagp)
{
    int f32 = *flagp;
    int row = blockIdx.x, tid = threadIdx.x;
    float4 v = ((const float4*)(X + (size_t)row * 1024))[tid];
    float s = v.x + v.y + v.z + v.w;
    float ss = v.x * v.x + v.y * v.y + v.z * v.z + v.w * v.w;
    float2 r = block_sum2(s, ss, tid);
    float mu = r.x * (1.f / 1024.f);
    float var = fmaxf(r.y * (1.f / 1024.f) - mu * mu, 0.f);
    float rs = rsqrtf(var + EPS);
    int n = row & 127;
    int c0 = tid * 4;
    float s0, s1, gv[4], bv[4], w0[4], w1[4], pb[4];
    if (f32) {
        s0 = ((const float*)sph_pos)[n * 2 + 0]; s1 = ((const float*)sph_pos)[n * 2 + 1];
        #pragma unroll
        for (int x = 0; x < 4; x++) {
            gv[x] = ((const float*)g)[c0 + x];  bv[x] = ((const float*)b)[c0 + x];
            w0[x] = ((const float*)pos_w)[c0 + x]; w1[x] = ((const float*)pos_w)[1024 + c0 + x];
            pb[x] = ((const float*)pos_b)[c0 + x];
        }
    } else {
        s0 = b2f(((const ushort*)sph_pos)[n * 2 + 0]); s1 = b2f(((const ushort*)sph_pos)[n * 2 + 1]);
        #pragma unroll
        for (int x = 0; x < 4; x++) {
            gv[x] = b2f(((const ushort*)g)[c0 + x]);  bv[x] = b2f(((const ushort*)b)[c0 + x]);
            w0[x] = b2f(((const ushort*)pos_w)[c0 + x]); w1[x] = b2f(((const ushort*)pos_w)[1024 + c0 + x]);
            pb[x] = b2f(((const ushort*)pos_b)[c0 + x]);
        }
    }
    float4 o;
    o.x = (v.x - mu) * rs * gv[0] + bv[0] + s0 * w0[0] + s1 * w1[0] + pb[0];
    o.y = (v.y - mu) * rs * gv[1] + bv[1] + s0 * w0[1] + s1 * w1[1] + pb[1];
    o.z = (v.z - mu) * rs * gv[2] + bv[2] + s0 * w0[2] + s1 * w1[2] + pb[2];
    o.w = (v.w - mu) * rs * gv[3] + bv[3] + s0 * w0[3] + s1 * w1[3] + pb[3];
    *(float4*)(X + (size_t)row * 1024 + c0) = o;
}

// ---------------------------------------------------------------------------
// Fused attention per (b, 16-row i-tile).  Grid 256 = 32 b x 8 itiles; one
// block per CU.  b = blockIdx&31 -> all 8 blocks of a b land on one XCD so
// K/V (512KB/b) stay in that XCD's L2.  (R7; neutral vs 3-kernel pipeline
// but -24 dispatches and less LLC pressure; kept.)
// ---------------------------------------------------------------------------
__global__ __launch_bounds__(256) void attn_fused(
    const ushort* __restrict__ qkv, const void* __restrict__ sph_dist,
    const int* __restrict__ flagp, ushort* __restrict__ o)
{
    __shared__ float dotsf[16 * 16 * 128];   // 128 KB: dots, then P/Vt overlay
    __shared__ float musd[16 * 128 * 2];     // 16 KB: (mu, rsd) per (i,j)
    const int tid = threadIdx.x, lane = tid & 63, w = tid >> 6;
    const int m16 = lane & 15, quad = lane >> 4;
    const int b = blockIdx.x & 31, i0 = (blockIdx.x >> 5) * 16;
    const int f32 = *flagp;

    // sph multipliers for this lane's output fragment (shared by 4 heads)
    float sphm[8][4];
    #pragma unroll
    for (int ct = 0; ct < 8; ct++)
        #pragma unroll
        for (int r = 0; r < 4; r++) {
            int i = i0 + quad * 4 + r, j = ct * 16 + m16;
            float sd = f32 ? ((const float*)sph_dist)[i * 128 + j]
                           : b2f(((const ushort*)sph_dist)[i * 128 + j]);
            sphm[ct][r] = 0.125f * (1.f + sd);
        }

    // ---- Phase A: QK^T (wave w owns heads 4w..4w+3) ----
    const ushort* qrow = qkv + (size_t)(b * 128 + i0 + m16) * 3072 + quad * 8;
    const ushort* krow = qkv + (size_t)(b * 128 + m16) * 3072 + 1024 + quad * 8;
    #pragma unroll
    for (int hh = 0; hh < 4; hh++) {
        const int h = w * 4 + hh;
        short8 qa0 = *(const short8*)(qrow + h * 64);
        short8 qa1 = *(const short8*)(qrow + h * 64 + 32);
        f32x4 acc[8];
        #pragma unroll
        for (int ct = 0; ct < 8; ct++) acc[ct] = (f32x4){0.f, 0.f, 0.f, 0.f};
        #pragma unroll
        for (int ct = 0; ct < 8; ct++) {
            const ushort* kp = krow + (size_t)ct * 16 * 3072 + h * 64;
            short8 k0 = *(const short8*)(kp);
            short8 k1 = *(const short8*)(kp + 32);
            acc[ct] = __builtin_amdgcn_mfma_f32_16x16x32_bf16(qa0, k0, acc[ct], 0, 0, 0);
            acc[ct] = __builtin_amdgcn_mfma_f32_16x16x32_bf16(qa1, k1, acc[ct], 0, 0, 0);
        }
        #pragma unroll
        for (int ct = 0; ct < 8; ct++)
            #pragma unroll
            for (int r = 0; r < 4; r++)
                dotsf[h * 2048 + (quad * 4 + r) * 128 + ct * 16 + m16] =
                    acc[ct][r] * sphm[ct][r];
    }
    __syncthreads();

    // ---- Phase B: cross-head mean / 1/std per (i,j) ----
    #pragma unroll
    for (int p = 0; p < 8; p++) {
        int idx = p * 256 + tid, i = idx >> 7, j = idx & 127;
        float v[16], s = 0.f;
        #pragma unroll
        for (int h = 0; h < 16; h++) { v[h] = dotsf[h * 2048 + i * 128 + j]; s += v[h]; }
        float mu = s * (1.f / 16.f), q = 0.f;
        #pragma unroll
        for (int h = 0; h < 16; h++) { float d = v[h] - mu; q += d * d; }
        float rsd = rsqrtf(fmaxf(q * (1.f / 15.f), 1e-20f));
        musd[(i * 128 + j) * 2]     = mu;
        musd[(i * 128 + j) * 2 + 1] = rsd;
    }
    __syncthreads();

    // ---- Phase C: row softmax, P packed in-place (lane owns j=2l,2l+1) ----
    #pragma unroll
    for (int hh = 0; hh < 4; hh++) {
        const int h = w * 4 + hh;
        #pragma unroll
        for (int i = 0; i < 16; i++) {
            float x0 = dotsf[h * 2048 + i * 128 + 2 * lane];
            float x1 = dotsf[h * 2048 + i * 128 + 2 * lane + 1];
            float4 ms = *(const float4*)&musd[i * 256 + 4 * lane];
            x0 = (x0 - ms.x) * ms.y;
            x1 = (x1 - ms.z) * ms.w;
            float m = fmaxf(x0, x1);
            #pragma unroll
            for (int o2 = 32; o2; o2 >>= 1) m = fmaxf(m, __shfl_xor(m, o2));
            float e0 = __expf(x0 - m), e1 = __expf(x1 - m);
            float s = e0 + e1;
            #pragma unroll
            for (int o2 = 32; o2; o2 >>= 1) s += __shfl_xor(s, o2);
            float inv = 1.f / s;
            dotsf[h * 2048 + i * 64 + (lane ^ ((i & 7) << 2))] =
                pack2(f2b(e0 * inv), f2b(e1 * inv));
        }
    }
    __syncthreads();

    // ---- Phase E: per head: stage V^T into freed halves, PV, store o ----
    #pragma unroll 1
    for (int g = 0; g < 4; g++) {
        const int h = w * 4 + g;
        {
            // lane stages V rows 2l, 2l+1; word (d, pair l) = (V[2l][d], V[2l+1][d])
            const ushort* vr0 = qkv + (size_t)(b * 128 + 2 * lane) * 3072 + 2048 + h * 64;
            const ushort* vr1 = vr0 + 3072;
            short8 r0[8], r1[8];
            #pragma unroll
            for (int x = 0; x < 8; x++) {
                r0[x] = *(const short8*)(vr0 + x * 8);
                r1[x] = *(const short8*)(vr1 + x * 8);
            }
            #pragma unroll
            for (int d = 0; d < 64; d++)
                dotsf[(w * 4 + (d >> 4)) * 2048 + 1024 + (d & 15) * 64 +
                      (lane ^ ((d & 7) << 2))] =
                    pack2((ushort)r0[d >> 3][d & 7], (ushort)r1[d >> 3][d & 7]);
        }
        __syncthreads();
        f32x4 pacc[4];
        #pragma unroll
        for (int ct = 0; ct < 4; ct++) pacc[ct] = (f32x4){0.f, 0.f, 0.f, 0.f};
        const int sw = (m16 & 7) << 2;
        #pragma unroll
        for (int kq = 0; kq < 4; kq++) {
            f32x4 paw = *(const f32x4*)&dotsf[h * 2048 + m16 * 64 +
                                              ((kq * 16 + quad * 4) ^ sw)];
            short8 pa = as_short8(paw);
            #pragma unroll
            for (int ct = 0; ct < 4; ct++) {
                f32x4 vbw = *(const f32x4*)&dotsf[(w * 4 + ct) * 2048 + 1024 + m16 * 64 +
                                                  ((kq * 16 + quad * 4) ^ sw)];
                pacc[ct] = __builtin_amdgcn_mfma_f32_16x16x32_bf16(pa, as_short8(vbw), pacc[ct], 0, 0, 0);
            }
        }
        #pragma unroll
        for (int ct = 0; ct < 4; ct++)
            #pragma unroll
            for (int r = 0; r < 4; r++)
                o[(size_t)(b * 128 + i0 + quad * 4 + r) * 1024 + h * 64 + ct * 16 + m16] =
                    f2b(pacc[ct][r]);
        __syncthreads();
    }
}

// ---------------------------------------------------------------------------
// Final LN over 3072 (bf16 in) + un-patchify; writes fp32 OR bf16 per flag.
// ---------------------------------------------------------------------------
__global__ __launch_bounds__(256) void out_ln_rearrange(
    const ushort* __restrict__ Y, const void* __restrict__ g,
    const void* __restrict__ bb, const int* __restrict__ flagp,
    void* __restrict__ out)
{
    __shared__ float rowbuf[3072];
    int f32 = *flagp;
    int r = blockIdx.x;
    int b = r >> 7, n = r & 127, hg = n >> 4, wg = n & 15;
    int tid = threadIdx.x;
    float s = 0.f, ss = 0.f;
    #pragma unroll
    for (int x = 0; x < 3; x++) {
        ushort4 u = *(const ushort4*)(Y + (size_t)r * 3072 + (size_t)(x * 256 + tid) * 4);
        float4 v = make_float4(b2f(u.x), b2f(u.y), b2f(u.z), b2f(u.w));
        *(float4*)(rowbuf + (x * 256 + tid) * 4) = v;
        s += v.x + v.y + v.z + v.w;
        ss += v.x * v.x + v.y * v.y + v.z * v.z + v.w * v.w;
    }
    float2 red = block_sum2(s, ss, tid);   // barrier makes rowbuf visible
    float mu = red.x * (1.f / 3072.f);
    float var = fmaxf(red.y * (1.f / 3072.f) - mu * mu, 0.f);
    float rs = rsqrtf(var + EPS);
    int p1 = tid >> 3, sj = tid & 7;
    #pragma unroll
    for (int c = 0; c < 3; c++) {
        float vals[4];
        #pragma unroll
        for (int x = 0; x < 4; x++) {
            int p2 = sj * 4 + x;
            int col = p1 * 96 + p2 * 3 + c;
            float gv, bv;
            if (f32) { gv = ((const float*)g)[col];  bv = ((const float*)bb)[col]; }
            else     { gv = b2f(((const ushort*)g)[col]); bv = b2f(((const ushort*)bb)[col]); }
            vals[x] = (rowbuf[col] - mu) * rs * gv + bv;
        }
        size_t di = (size_t)((b * 3 + c) * 256 + hg * 32 + p1) * 512 + wg * 32 + sj * 4;
        if (f32) {
            *(float4*)((float*)out + di) = make_float4(vals[0], vals[1], vals[2], vals[3]);
        } else {
            ushort4 o4;
            #pragma unroll
            for (int x = 0; x < 4; x++) ((ushort*)&o4)[x] = f2b(vals[x]);
            *(ushort4*)((ushort*)out + di) = o4;
        }
    }
}

// ---------------------------------------------------------------------------
// Host-side orchestration
// ---------------------------------------------------------------------------
extern "C" void kernel_launch(void* const* d_in, const int* in_sizes, int n_in,
                              void* d_out, int out_size, void* d_ws, size_t ws_size,
                              hipStream_t stream)
{
    const void* img      = d_in[0];
    const void* sph_pos  = d_in[1];
    const void* sph_dist = d_in[2];
    const void* conv_w   = d_in[3];
    const void* conv_b   = d_in[4];
    const void* nl1g     = d_in[5];
    const void* nl1b     = d_in[6];
    const void* nl_w     = d_in[7];
    const void* nl_b     = d_in[8];
    const void* nl2g     = d_in[9];
    const void* nl2b     = d_in[10];
    const void* pos_w    = d_in[11];
    const void* pos_b    = d_in[12];
    const void* ln_g     = d_in[13];
    const void* ln_b     = d_in[14];
    const void* wqkv     = d_in[15];
    const void* wo       = d_in[16];
    const void* wo_b     = d_in[17];
    const void* trg      = d_in[18];
    const void* trb      = d_in[19];
    const void* exp_w    = d_in[20];
    const void* exp_b    = d_in[21];
    const void* og       = d_in[22];
    const void* ob       = d_in[23];

    // --- workspace layout: 88 MiB + flag ---
    char* ws = (char*)d_ws;
    float*  xf    = (float*) (ws + 0);            // [0,16M)   fp32 residual [4096,1024]
    ushort* xb    = (ushort*)(ws + 16777216);     // [16,24M)  bf16 LN out [4096,1024]
    ushort* qkvb  = (ushort*)(ws + 25165824);     // [24,48M)  bf16 qkv / patch-mat / expand-out
    float*  y1    = (float*) (ws + 50331648);     // fp32 patch-embed out (pre-loop)
    ushort* o_bf  = (ushort*)(ws + 50331648);     // overlay: bf16 attn out (in loop)
    ushort* wTa   = (ushort*)(ws + 83886080);     // [80,86M)  weight^T [3072,1024]
    ushort* wTb   = (ushort*)(ws + 90177536);     // [86,88M)  weight^T [1024,1024]
    int*    flagp = (int*)   (ws + 92274688);     // dtype flag (1 = fp32 world)

    sniff_dtype<<<1, 64, 0, stream>>>((const uint32_t*)nl1g, flagp);

    // patch embedding (patch matrix staged in qkvb region)
    patch_gather<<<6144, 256, 0, stream>>>(img, qkvb, flagp);
    convert_copy<<<1536, 256, 0, stream>>>(conv_w, wTa, flagp);   // 1024x3072 -> bf16
    gemm_nt<0><<<dim3(8, 32), 256, 0, stream>>>(qkvb, wTa, conv_b, 0, flagp, y1, nullptr,
                                                4096, 1024, 3072, 3072, 3072, 1024, 4, 8);
    // norm_linear
    ln_f32_to_bf16<<<4096, 256, 0, stream>>>(y1, nl1g, nl1b, 0, flagp, xb);
    transpose_k<<<dim3(32, 32), 256, 0, stream>>>(nl_w, 0, wTb, 1024, 1024, flagp);
    gemm_nt<0><<<dim3(8, 32), 256, 0, stream>>>(xb, wTb, nl_b, 0, flagp, xf, nullptr,
                                                4096, 1024, 1024, 1024, 1024, 1024, 4, 8);
    ln2_pos<<<4096, 256, 0, stream>>>(xf, nl2g, nl2b, sph_pos, pos_w, pos_b, flagp);

    // transformer blocks
    for (int l = 0; l < 12; l++) {
        transpose_k<<<dim3(96, 32), 256, 0, stream>>>(wqkv, (size_t)l * 1024 * 3072, wTa, 1024, 3072, flagp);
        transpose_k<<<dim3(32, 32), 256, 0, stream>>>(wo, (size_t)l * 1024 * 1024, wTb, 1024, 1024, flagp);
        ln_f32_to_bf16<<<4096, 256, 0, stream>>>(xf, ln_g, ln_b, l * 1024, flagp, xb);
        gemm_nt<1><<<dim3(24, 32), 256, 0, stream>>>(xb, wTa, nullptr, 0, flagp, nullptr, qkvb,
                                                     4096, 3072, 1024, 1024, 1024, 3072, 8, 12);
        attn_fused<<<256, 256, 0, stream>>>(qkvb, sph_dist, flagp, o_bf);
        gemm_nt<2><<<dim3(8, 32), 256, 0, stream>>>(o_bf, wTb, wo_b, l * 1024, flagp, xf, nullptr,
                                                    4096, 1024, 1024, 1024, 1024, 1024, 4, 8);
    }

    // final LN + expand head (bf16 into qkvb) + un-patchify (dtype per flag)
    ln_f32_to_bf16<<<4096, 256, 0, stream>>>(xf, trg, trb, 0, flagp, xb);
    transpose_k<<<dim3(96, 32), 256, 0, stream>>>(exp_w, 0, wTa, 1024, 3072, flagp);
    gemm_nt<1><<<dim3(24, 32), 256, 0, stream>>>(xb, wTa, exp_b, 0, flagp, nullptr, qkvb,
                                                 4096, 3072, 1024, 1024, 1024, 3072, 8, 12);
    out_ln_rearrange<<<4096, 256, 0, stream>>>(qkvb, og, ob, flagp, d_out);
}